// Round 1
// baseline (308.990 us; speedup 1.0000x reference)
//
#include <hip/hip_runtime.h>

// RNN scan: h_{t+1} = relu(W_hh @ h_t + x_t * w_x), out = W_hy @ h_T
// B=8192, T=512, H=64.
// Mapping: 1 wave = 32 batch columns (N), full M=K=64.
//   C = W_hh (A, resident in regs, 8 frags) x h (B operand, rebuilt per step).
//   32x32x16 bf16 MFMA; k-blocks m=0..3; tiles tau=0 (rows 0-31) / 1 (rows 32-63).
//   C layout: col=lane&31 (batch), row=(reg&3)+8*(reg>>2)+4*(lane>>5)  [verified m74/m101]
//   B layout: col=lane&31 (batch), k=8*(lane>>5)+e, e=0..7
//   => batch stays lane-local; h->B remap is only a lane l <-> l^32 exchange.
// x term and accumulation are f32-exact; only W_hh*h goes through bf16
// (contraction ||W_hh|| ~ 0.16 => no error accumulation across steps).

typedef __bf16 bf16x8 __attribute__((ext_vector_type(8)));
typedef float f32x16 __attribute__((ext_vector_type(16)));
typedef unsigned int u32x4 __attribute__((ext_vector_type(4)));

#define RNN_B 8192
#define RNN_T 512
#define RNN_H 64

__device__ __forceinline__ unsigned pk2_relu(float a, float b) {
  float ra = fmaxf(a, 0.0f), rb = fmaxf(b, 0.0f);
  unsigned short ua = __builtin_bit_cast(unsigned short, (__bf16)ra);
  unsigned short ub = __builtin_bit_cast(unsigned short, (__bf16)rb);
  return (unsigned)ua | ((unsigned)ub << 16);
}

__global__ __launch_bounds__(64, 1) void rnn_scan_kernel(
    const float* __restrict__ x,
    const float* __restrict__ Wxh,
    const float* __restrict__ Whh,
    const float* __restrict__ Why,
    float* __restrict__ out)
{
  const int lane = threadIdx.x;
  const int col  = lane & 31;   // batch within wave; also A-row / B-col lane index
  const int sel  = lane >> 5;
  const int b0   = blockIdx.x * 32;

  // ---- A fragments: W_hh[i][j], i = 32*tau + col, j = 16*m + 8*sel + e ----
  bf16x8 A[2][4];
#pragma unroll
  for (int tau = 0; tau < 2; ++tau) {
#pragma unroll
    for (int m = 0; m < 4; ++m) {
      const float* wp = Whh + (32 * tau + col) * RNN_H + 16 * m + 8 * sel;
      float4 w0 = *(const float4*)(wp);
      float4 w1 = *(const float4*)(wp + 4);
      bf16x8 f;
      f[0] = (__bf16)w0.x; f[1] = (__bf16)w0.y; f[2] = (__bf16)w0.z; f[3] = (__bf16)w0.w;
      f[4] = (__bf16)w1.x; f[5] = (__bf16)w1.y; f[6] = (__bf16)w1.z; f[7] = (__bf16)w1.w;
      A[tau][m] = f;
    }
  }

  // ---- w_x per accumulator slot (row of C this reg holds) ----
  float wx0[16], wx1[16];
#pragma unroll
  for (int r = 0; r < 16; ++r) {
    const int row = (r & 3) + 8 * (r >> 2) + 4 * sel;
    wx0[r] = Wxh[row];
    wx1[r] = Wxh[row + 32];
  }

  const float* xrow = x + (size_t)(b0 + col) * RNN_T;
  float4 xc0 = *(const float4*)(xrow);
  float4 xc1 = *(const float4*)(xrow + 4);

  f32x16 acc0, acc1;              // pre-relu h, rows 0-31 / 32-63
  unsigned bf[4][4];              // bf16 B-fragments of h_t (h_0 = 0)
#pragma unroll
  for (int m = 0; m < 4; ++m)
#pragma unroll
    for (int r = 0; r < 4; ++r) bf[m][r] = 0u;

  for (int tb = 0; tb < RNN_T; tb += 8) {
    const int tn = (tb + 8 < RNN_T) ? tb + 8 : tb;   // prefetch (clamped tail)
    float4 xn0 = *(const float4*)(xrow + tn);
    float4 xn1 = *(const float4*)(xrow + tn + 4);
    const float xs[8] = {xc0.x, xc0.y, xc0.z, xc0.w, xc1.x, xc1.y, xc1.z, xc1.w};
#pragma unroll
    for (int j = 0; j < 8; ++j) {
      const float xv = xs[j];
      // acc init: f32-exact x_t * w_x
#pragma unroll
      for (int r = 0; r < 16; ++r) {
        acc0[r] = xv * wx0[r];
        acc1[r] = xv * wx1[r];
      }
      // acc += W_hh * h_t
#pragma unroll
      for (int m = 0; m < 4; ++m) {
        u32x4 u = {bf[m][0], bf[m][1], bf[m][2], bf[m][3]};
        bf16x8 Bv = __builtin_bit_cast(bf16x8, u);
        acc0 = __builtin_amdgcn_mfma_f32_32x32x16_bf16(A[0][m], Bv, acc0, 0, 0, 0);
        acc1 = __builtin_amdgcn_mfma_f32_32x32x16_bf16(A[1][m], Bv, acc1, 0, 0, 0);
      }
      // h_{t+1} = relu(acc); rebuild B-fragments.
      // Block m covers comps [16m,16m+16): quads q0..q3.
      // lower lane holds q0 (regs base+0..3), q2 (base+4..7); upper holds q1,q3.
      // lower lane frag needs [q0|q1], upper needs [q2|q3] -> l <-> l^32 exchange.
#pragma unroll
      for (int m = 0; m < 4; ++m) {
        const f32x16 a = (m < 2) ? acc0 : acc1;     // m literal -> folds
        const int base = (m & 1) * 8;
        unsigned X0 = pk2_relu(a[base + 0], a[base + 1]);
        unsigned X1 = pk2_relu(a[base + 2], a[base + 3]);
        unsigned Y0 = pk2_relu(a[base + 4], a[base + 5]);
        unsigned Y1 = pk2_relu(a[base + 6], a[base + 7]);
        unsigned X0p = __shfl_xor(X0, 32, 64);
        unsigned X1p = __shfl_xor(X1, 32, 64);
        unsigned Y0p = __shfl_xor(Y0, 32, 64);
        unsigned Y1p = __shfl_xor(Y1, 32, 64);
        bf[m][0] = sel ? Y0p : X0;   // e0,e1
        bf[m][1] = sel ? Y1p : X1;   // e2,e3
        bf[m][2] = sel ? Y0  : X0p;  // e4,e5
        bf[m][3] = sel ? Y1  : X1p;  // e6,e7
      }
    }
    xc0 = xn0; xc1 = xn1;
  }

  // ---- epilogue: out[b] = sum_i Why[i] * relu(h_pre[i]) (f32) ----
  float p = 0.0f;
#pragma unroll
  for (int r = 0; r < 16; ++r) {
    const int row = (r & 3) + 8 * (r >> 2) + 4 * sel;
    p += Why[row]      * fmaxf(acc0[r], 0.0f);
    p += Why[row + 32] * fmaxf(acc1[r], 0.0f);
  }
  p += __shfl_xor(p, 32, 64);
  if (lane < 32) out[b0 + col] = p;
}

extern "C" void kernel_launch(void* const* d_in, const int* in_sizes, int n_in,
                              void* d_out, int out_size, void* d_ws, size_t ws_size,
                              hipStream_t stream) {
  const float* x   = (const float*)d_in[0];
  const float* Wxh = (const float*)d_in[1];
  const float* Whh = (const float*)d_in[2];
  const float* Why = (const float*)d_in[3];
  float* out = (float*)d_out;
  (void)in_sizes; (void)n_in; (void)out_size; (void)d_ws; (void)ws_size;
  rnn_scan_kernel<<<dim3(RNN_B / 32), dim3(64), 0, stream>>>(x, Wxh, Whh, Why, out);
}

// Round 3
// 257.410 us; speedup vs baseline: 1.2004x; 1.2004x over previous
//
#include <hip/hip_runtime.h>

// RNN scan: h_{t+1} = relu(W_hh @ h_t + x_t * w_x), out = W_hy @ h_T
// B=8192, T=512, H=64.  Latency-bound: 1 wave = 32 batch cols, wallclock =
// 512 x per-step critical path.
//   - MFMA chains split 4-deep -> 2x2-deep (merge via pk_add before relu)
//   - h->B-fragment remap via v_permlane32_swap_b32 (VALU) instead of
//     ds-permute __shfl_xor + cndmask selects
// permlane32_swap semantics (gfx950): VDST.hi32 <-> SRC0.lo32, i.e. with
// operands (X, Y):  X' = {lo: self X | hi: Y from lane-32}
//                   Y' = {lo: X from lane+32 | hi: self Y}
// (round-2 bug: operands were (Y, X) -> quad-reversed k-permutation ->
//  absmax 8.6e-5; matches T12's (low-quad-first) usage now.)
// C layout: col=lane&31 (batch), row=(reg&3)+8*(reg>>2)+4*(lane>>5)
// B layout: col=lane&31, k=8*(lane>>5)+e  => batch stays lane-local.

typedef __bf16 bf16x8 __attribute__((ext_vector_type(8)));
typedef float f32x16 __attribute__((ext_vector_type(16)));
typedef unsigned int u32x4 __attribute__((ext_vector_type(4)));

#define RNN_B 8192
#define RNN_T 512
#define RNN_H 64

__device__ __forceinline__ unsigned pk2_relu(float a, float b) {
  float ra = fmaxf(a, 0.0f), rb = fmaxf(b, 0.0f);
  unsigned short ua = __builtin_bit_cast(unsigned short, (__bf16)ra);
  unsigned short ub = __builtin_bit_cast(unsigned short, (__bf16)rb);
  return (unsigned)ua | ((unsigned)ub << 16);
}

__global__ __launch_bounds__(64, 1) void rnn_scan_kernel(
    const float* __restrict__ x,
    const float* __restrict__ Wxh,
    const float* __restrict__ Whh,
    const float* __restrict__ Why,
    float* __restrict__ out)
{
  const int lane = threadIdx.x;
  const int col  = lane & 31;
  const int sel  = lane >> 5;
  const int b0   = blockIdx.x * 32;

  // ---- A fragments: W_hh[i][j], i = 32*tau + col, j = 16*m + 8*sel + e ----
  bf16x8 A[2][4];
#pragma unroll
  for (int tau = 0; tau < 2; ++tau) {
#pragma unroll
    for (int m = 0; m < 4; ++m) {
      const float* wp = Whh + (32 * tau + col) * RNN_H + 16 * m + 8 * sel;
      float4 w0 = *(const float4*)(wp);
      float4 w1 = *(const float4*)(wp + 4);
      bf16x8 f;
      f[0] = (__bf16)w0.x; f[1] = (__bf16)w0.y; f[2] = (__bf16)w0.z; f[3] = (__bf16)w0.w;
      f[4] = (__bf16)w1.x; f[5] = (__bf16)w1.y; f[6] = (__bf16)w1.z; f[7] = (__bf16)w1.w;
      A[tau][m] = f;
    }
  }

  // ---- w_x per accumulator slot ----
  f32x16 wx0v, wx1v;
#pragma unroll
  for (int r = 0; r < 16; ++r) {
    const int row = (r & 3) + 8 * (r >> 2) + 4 * sel;
    wx0v[r] = Wxh[row];
    wx1v[r] = Wxh[row + 32];
  }

  const float* xrow = x + (size_t)(b0 + col) * RNN_T;
  float4 xc0 = *(const float4*)(xrow);
  float4 xc1 = *(const float4*)(xrow + 4);

  f32x16 zf = {};
  f32x16 hpre0 = zf, hpre1 = zf;       // final-step pre-relu h
  unsigned bf[4][4];                    // bf16 B-fragments of h_t (h_0 = 0)
#pragma unroll
  for (int m = 0; m < 4; ++m)
#pragma unroll
    for (int r = 0; r < 4; ++r) bf[m][r] = 0u;

  for (int tb = 0; tb < RNN_T; tb += 8) {
    const int tn = (tb + 8 < RNN_T) ? tb + 8 : tb;
    float4 xn0 = *(const float4*)(xrow + tn);
    float4 xn1 = *(const float4*)(xrow + tn + 4);
    const float xs[8] = {xc0.x, xc0.y, xc0.z, xc0.w, xc1.x, xc1.y, xc1.z, xc1.w};
#pragma unroll
    for (int j = 0; j < 8; ++j) {
      const float xv = xs[j];
      // f32-exact x_t * w_x as C-in of chain A
      f32x16 i0 = wx0v * xv;
      f32x16 i1 = wx1v * xv;

      u32x4 u0 = {bf[0][0], bf[0][1], bf[0][2], bf[0][3]};
      u32x4 u1 = {bf[1][0], bf[1][1], bf[1][2], bf[1][3]};
      u32x4 u2 = {bf[2][0], bf[2][1], bf[2][2], bf[2][3]};
      u32x4 u3 = {bf[3][0], bf[3][1], bf[3][2], bf[3][3]};
      bf16x8 B0 = __builtin_bit_cast(bf16x8, u0);
      bf16x8 B1 = __builtin_bit_cast(bf16x8, u1);
      bf16x8 B2 = __builtin_bit_cast(bf16x8, u2);
      bf16x8 B3 = __builtin_bit_cast(bf16x8, u3);

      // 4 independent chains of depth 2 (was: 2 chains of depth 4)
      f32x16 a0A = __builtin_amdgcn_mfma_f32_32x32x16_bf16(A[0][0], B0, i0, 0, 0, 0);
      f32x16 a1A = __builtin_amdgcn_mfma_f32_32x32x16_bf16(A[1][0], B0, i1, 0, 0, 0);
      f32x16 a0B = __builtin_amdgcn_mfma_f32_32x32x16_bf16(A[0][2], B2, zf, 0, 0, 0);
      f32x16 a1B = __builtin_amdgcn_mfma_f32_32x32x16_bf16(A[1][2], B2, zf, 0, 0, 0);
      a0A = __builtin_amdgcn_mfma_f32_32x32x16_bf16(A[0][1], B1, a0A, 0, 0, 0);
      a1A = __builtin_amdgcn_mfma_f32_32x32x16_bf16(A[1][1], B1, a1A, 0, 0, 0);
      a0B = __builtin_amdgcn_mfma_f32_32x32x16_bf16(A[0][3], B3, a0B, 0, 0, 0);
      a1B = __builtin_amdgcn_mfma_f32_32x32x16_bf16(A[1][3], B3, a1B, 0, 0, 0);

      f32x16 s0 = a0A + a0B;   // v_pk_add_f32
      f32x16 s1 = a1A + a1B;
      hpre0 = s0; hpre1 = s1;

      // h_{t+1} = relu(s); rebuild B-fragments.
      // swap(X, Y): X' = {self X | partner Y} -> bf[.][0/1]
      //             Y' = {partner X | self Y} -> bf[.][2/3]
#pragma unroll
      for (int m = 0; m < 4; ++m) {
        const int base = (m & 1) * 8;
        unsigned X0, X1, Y0, Y1;
        if (m < 2) {
          X0 = pk2_relu(s0[base + 0], s0[base + 1]);
          X1 = pk2_relu(s0[base + 2], s0[base + 3]);
          Y0 = pk2_relu(s0[base + 4], s0[base + 5]);
          Y1 = pk2_relu(s0[base + 6], s0[base + 7]);
        } else {
          X0 = pk2_relu(s1[base + 0], s1[base + 1]);
          X1 = pk2_relu(s1[base + 2], s1[base + 3]);
          Y0 = pk2_relu(s1[base + 4], s1[base + 5]);
          Y1 = pk2_relu(s1[base + 6], s1[base + 7]);
        }
        asm volatile("v_permlane32_swap_b32 %0, %1" : "+v"(X0), "+v"(Y0));
        asm volatile("v_permlane32_swap_b32 %0, %1" : "+v"(X1), "+v"(Y1));
        bf[m][0] = X0;  // {self X | partner Y}
        bf[m][1] = X1;
        bf[m][2] = Y0;  // {partner X | self Y}
        bf[m][3] = Y1;
      }
    }
    xc0 = xn0; xc1 = xn1;
  }

  // ---- epilogue: out[b] = sum_i Why[i] * relu(h_pre[i]) (f32) ----
  float p = 0.0f;
#pragma unroll
  for (int r = 0; r < 16; ++r) {
    const int row = (r & 3) + 8 * (r >> 2) + 4 * sel;
    p += Why[row]      * fmaxf(hpre0[r], 0.0f);
    p += Why[row + 32] * fmaxf(hpre1[r], 0.0f);
  }
  p += __shfl_xor(p, 32, 64);
  if (lane < 32) out[b0 + col] = p;
}

extern "C" void kernel_launch(void* const* d_in, const int* in_sizes, int n_in,
                              void* d_out, int out_size, void* d_ws, size_t ws_size,
                              hipStream_t stream) {
  const float* x   = (const float*)d_in[0];
  const float* Wxh = (const float*)d_in[1];
  const float* Whh = (const float*)d_in[2];
  const float* Why = (const float*)d_in[3];
  float* out = (float*)d_out;
  (void)in_sizes; (void)n_in; (void)out_size; (void)d_ws; (void)ws_size;
  rnn_scan_kernel<<<dim3(RNN_B / 32), dim3(64), 0, stream>>>(x, Wxh, Whh, Why, out);
}